// Round 1
// baseline (1775.199 us; speedup 1.0000x reference)
//
#include <hip/hip_runtime.h>
#include <hip/hip_bf16.h>

// Problem constants
#define B 16
#define LP 128
#define LM 256
#define V 32000
#define E 512
#define H 512
#define DENC 1024          // 2*H
#define K1 2560            // E + 2*DENC
#define G4 2048            // 4*H

// d_out offsets (floats), concat order: logits, p_w, m_w, ctx_new, h1,c1,...,h4,c4
#define OFF_LOGITS 0
#define OFF_PW 512000
#define OFF_MW 514048
#define OFF_CTX 518144
#define OFF_H1 550912
#define OFF_C1 559104
#define OFF_H2 567296
#define OFF_C2 575488
#define OFF_H3 583680
#define OFF_C3 591872
#define OFF_H4 600064
#define OFF_C4 608256

// ws offsets (floats)
#define WS_X   0          // B*K1   = 40960
#define WS_Z   40960      // B*G4   = 32768
#define WS_D2P 73728      // B*H    = 8192
#define WS_D2M 81920      // B*H
#define WS_SP  90112      // B*LP   = 2048
#define WS_SM  92160      // B*LM   = 4096
#define WS_XX  96256      // B*K1   = 40960
// total 137216 floats = 549 KB

__device__ __forceinline__ float sigm(float x) { return 1.0f / (1.0f + expf(-x)); }

// ---------------- embedding gather + concat([ctx, emb]) ----------------
__global__ void k_embed(const int* __restrict__ word, const float* __restrict__ ctx,
                        const float* __restrict__ emb, float* __restrict__ x)
{
    int b = blockIdx.x;
    int w = word[b];
    for (int i = threadIdx.x; i < 2 * DENC; i += 256) x[b * K1 + i] = ctx[b * 2 * DENC + i];
    for (int i = threadIdx.x; i < E; i += 256)        x[b * K1 + 2 * DENC + i] = emb[(size_t)w * E + i];
}

// ---------------- z = x@Wx + h@Wh + b  (one thread per output column) ----------------
__global__ void k_lstm_z(const float* __restrict__ x, int kx,
                         const float* __restrict__ h,
                         const float* __restrict__ Wx, const float* __restrict__ Wh,
                         const float* __restrict__ bias, float* __restrict__ z)
{
    int b = blockIdx.y;
    int j = blockIdx.x * 256 + threadIdx.x;        // j in [0, 2048)
    const float* xr = x + (size_t)b * kx;
    const float* hr = h + (size_t)b * H;
    float acc = bias[j];
    #pragma unroll 4
    for (int k = 0; k < kx; ++k) acc += xr[k] * Wx[(size_t)k * G4 + j];
    #pragma unroll 4
    for (int k = 0; k < H; ++k)  acc += hr[k] * Wh[(size_t)k * G4 + j];
    z[b * G4 + j] = acc;
}

// ---------------- LSTM gates ----------------
__global__ void k_gates(const float* __restrict__ z, const float* __restrict__ c_old,
                        float* __restrict__ h_new, float* __restrict__ c_new)
{
    int b = blockIdx.y;
    int j = blockIdx.x * 256 + threadIdx.x;        // j in [0, 512)
    float zi = z[b * G4 + j];
    float zf = z[b * G4 + H + j];
    float zg = z[b * G4 + 2 * H + j];
    float zo = z[b * G4 + 3 * H + j];
    float c = sigm(zf) * c_old[b * H + j] + sigm(zi) * tanhf(zg);
    float hh = sigm(zo) * tanhf(c);
    c_new[b * H + j] = c;
    h_new[b * H + j] = hh;
}

// ---------------- d2 = h4@W2 + W2b  (both attentions) ----------------
__global__ void k_decproj(const float* __restrict__ h4,
                          const float* __restrict__ pW2w, const float* __restrict__ pW2b,
                          const float* __restrict__ mW2w, const float* __restrict__ mW2b,
                          float* __restrict__ d2p, float* __restrict__ d2m)
{
    int b = blockIdx.y;
    int j = blockIdx.x * 256 + threadIdx.x;        // j in [0, 512)
    int which = blockIdx.z;
    const float* W = which ? mW2w : pW2w;
    const float* bb = which ? mW2b : pW2b;
    float* o = which ? d2m : d2p;
    const float* hr = h4 + b * H;
    float acc = bb[j];
    #pragma unroll 4
    for (int k = 0; k < H; ++k) acc += hr[k] * W[k * H + j];
    o[b * H + j] = acc;
}

// ---------------- attention scores: s[b,l] = tanh(enc@W1 + W1b + d2)·V + Vb ----------------
#define TL 16
#define CH 128
__global__ void k_attscore(const float* __restrict__ encP, const float* __restrict__ encM,
                           const float* __restrict__ pW1w, const float* __restrict__ pW1b,
                           const float* __restrict__ pVw,  const float* __restrict__ pVb,
                           const float* __restrict__ mW1w, const float* __restrict__ mW1b,
                           const float* __restrict__ mVw,  const float* __restrict__ mVb,
                           const float* __restrict__ d2p,  const float* __restrict__ d2m,
                           float* __restrict__ sp, float* __restrict__ sm)
{
    __shared__ float smem[4352];                    // max(CH*20=2560, 256*17=4352)
    int tile = blockIdx.x, b = blockIdx.y, tid = threadIdx.x;
    const int PT = LP / TL;                         // 8 persona tiles
    const float *enc, *W1, *W1bv, *Vw, *Vbv, *d2;
    float* sout; int L, l0;
    if (tile < PT) { enc = encP; W1 = pW1w; W1bv = pW1b; Vw = pVw; Vbv = pVb; d2 = d2p; sout = sp; L = LP; l0 = tile * TL; }
    else           { enc = encM; W1 = mW1w; W1bv = mW1b; Vw = mVw; Vbv = mVb; d2 = d2m; sout = sm; L = LM; l0 = (tile - PT) * TL; }

    float accA[TL], accB[TL];
    #pragma unroll
    for (int l = 0; l < TL; ++l) { accA[l] = 0.f; accB[l] = 0.f; }

    for (int kk0 = 0; kk0 < DENC; kk0 += CH) {
        __syncthreads();
        for (int idx = tid; idx < CH * TL; idx += 256) {
            int kk = idx & (CH - 1), ll = idx >> 7;
            smem[kk * 20 + ll] = enc[(size_t)(b * L + l0 + ll) * DENC + kk0 + kk];
        }
        __syncthreads();
        for (int kk = 0; kk < CH; ++kk) {
            float wa = W1[(size_t)(kk0 + kk) * H + tid];
            float wb = W1[(size_t)(kk0 + kk) * H + 256 + tid];
            float el[TL];
            #pragma unroll
            for (int q = 0; q < TL / 4; ++q) {
                float4 t = *(const float4*)&smem[kk * 20 + q * 4];
                el[q * 4 + 0] = t.x; el[q * 4 + 1] = t.y; el[q * 4 + 2] = t.z; el[q * 4 + 3] = t.w;
            }
            #pragma unroll
            for (int l = 0; l < TL; ++l) { accA[l] += el[l] * wa; accB[l] += el[l] * wb; }
        }
    }

    float vA = Vw[tid], vB = Vw[256 + tid];
    float cA = W1bv[tid] + d2[b * H + tid];
    float cB = W1bv[256 + tid] + d2[b * H + 256 + tid];
    float contrib[TL];
    #pragma unroll
    for (int l = 0; l < TL; ++l)
        contrib[l] = tanhf(accA[l] + cA) * vA + tanhf(accB[l] + cB) * vB;

    __syncthreads();
    #pragma unroll
    for (int l = 0; l < TL; ++l) smem[tid * 17 + l] = contrib[l];
    __syncthreads();
    if (tid < TL) {
        float s = Vbv[0];
        for (int t = 0; t < 256; ++t) s += smem[t * 17 + tid];
        sout[b * L + l0 + tid] = s;
    }
}

// ---------------- softmax over L + weighted ctx, writes w and ctx_new to d_out ----------------
__global__ void k_softmax_ctx(const float* __restrict__ encP, const float* __restrict__ encM,
                              const float* __restrict__ sp, const float* __restrict__ sm,
                              float* __restrict__ out)
{
    int b = blockIdx.x, which = blockIdx.y, tid = threadIdx.x;
    const float* enc = which ? encM : encP;
    const float* s   = which ? sm : sp;
    int L = which ? LM : LP;
    float* wdst = out + (which ? (OFF_MW + b * LM) : (OFF_PW + b * LP));

    __shared__ float red[256];
    __shared__ float wsh[256];
    float v = (tid < L) ? s[b * L + tid] : -3.4e38f;
    red[tid] = v; __syncthreads();
    for (int off = 128; off > 0; off >>= 1) { if (tid < off) red[tid] = fmaxf(red[tid], red[tid + off]); __syncthreads(); }
    float mx = red[0]; __syncthreads();
    float e = (tid < L) ? expf(v - mx) : 0.f;
    red[tid] = e; __syncthreads();
    for (int off = 128; off > 0; off >>= 1) { if (tid < off) red[tid] += red[tid + off]; __syncthreads(); }
    float w = e / red[0];
    wsh[tid] = w;
    if (tid < L) wdst[tid] = w;
    __syncthreads();

    for (int d = tid; d < DENC; d += 256) {
        float acc = 0.f;
        for (int l = 0; l < L; ++l) acc += wsh[l] * enc[(size_t)(b * L + l) * DENC + d];
        out[OFF_CTX + b * 2 * DENC + which * DENC + d] = acc;
    }
}

// ---------------- build xx = concat([h4, ctx_new]) ----------------
__global__ void k_buildxx(const float* __restrict__ out, float* __restrict__ xx)
{
    int b = blockIdx.x;
    for (int i = threadIdx.x; i < H; i += 256)        xx[b * K1 + i] = out[OFF_H4 + b * H + i];
    for (int i = threadIdx.x; i < 2 * DENC; i += 256) xx[b * K1 + H + i] = out[OFF_CTX + b * 2 * DENC + i];
}

// ---------------- logits init (bias) ----------------
__global__ void k_loginit(const float* __restrict__ ob, float* __restrict__ out)
{
    int v = blockIdx.x * 256 + threadIdx.x;
    out[(size_t)blockIdx.y * V + v] = ob[v];
}

// ---------------- logits GEMM: out[b][v] += sum_k xx[b][k]*out_w[k][v], K-split via atomics ----------------
#define KSPLIT 2
__global__ void k_logits(const float* __restrict__ xx, const float* __restrict__ ow,
                         float* __restrict__ out)
{
    int v = blockIdx.x * 256 + threadIdx.x;
    int k0 = blockIdx.y * (K1 / KSPLIT);
    float acc[B];
    #pragma unroll
    for (int b = 0; b < B; ++b) acc[b] = 0.f;
    #pragma unroll 4
    for (int k = k0; k < k0 + K1 / KSPLIT; ++k) {
        float w = ow[(size_t)k * V + v];
        #pragma unroll
        for (int b = 0; b < B; ++b) acc[b] += xx[b * K1 + k] * w;
    }
    #pragma unroll
    for (int b = 0; b < B; ++b) atomicAdd(&out[(size_t)b * V + v], acc[b]);
}

extern "C" void kernel_launch(void* const* d_in, const int* in_sizes, int n_in,
                              void* d_out, int out_size, void* d_ws, size_t ws_size,
                              hipStream_t stream)
{
    const int*   word = (const int*)d_in[0];
    const float* encP = (const float*)d_in[1];
    const float* encM = (const float*)d_in[2];
    const float* ctx  = (const float*)d_in[3];
    const float* h1o  = (const float*)d_in[4];
    const float* c1o  = (const float*)d_in[5];
    const float* h2o  = (const float*)d_in[6];
    const float* c2o  = (const float*)d_in[7];
    const float* h3o  = (const float*)d_in[8];
    const float* c3o  = (const float*)d_in[9];
    const float* h4o  = (const float*)d_in[10];
    const float* c4o  = (const float*)d_in[11];
    const float* emb  = (const float*)d_in[12];
    const float* Wx1 = (const float*)d_in[13]; const float* Wh1 = (const float*)d_in[14]; const float* b1 = (const float*)d_in[15];
    const float* Wx2 = (const float*)d_in[16]; const float* Wh2 = (const float*)d_in[17]; const float* b2 = (const float*)d_in[18];
    const float* Wx3 = (const float*)d_in[19]; const float* Wh3 = (const float*)d_in[20]; const float* b3 = (const float*)d_in[21];
    const float* Wx4 = (const float*)d_in[22]; const float* Wh4 = (const float*)d_in[23]; const float* b4 = (const float*)d_in[24];
    const float* pW1w = (const float*)d_in[25]; const float* pW1b = (const float*)d_in[26];
    const float* pW2w = (const float*)d_in[27]; const float* pW2b = (const float*)d_in[28];
    const float* pVw  = (const float*)d_in[29]; const float* pVb  = (const float*)d_in[30];
    const float* mW1w = (const float*)d_in[31]; const float* mW1b = (const float*)d_in[32];
    const float* mW2w = (const float*)d_in[33]; const float* mW2b = (const float*)d_in[34];
    const float* mVw  = (const float*)d_in[35]; const float* mVb  = (const float*)d_in[36];
    const float* outw = (const float*)d_in[37]; const float* outb = (const float*)d_in[38];

    float* out = (float*)d_out;
    float* ws  = (float*)d_ws;
    float* X   = ws + WS_X;
    float* Z   = ws + WS_Z;
    float* D2P = ws + WS_D2P;
    float* D2M = ws + WS_D2M;
    float* SP  = ws + WS_SP;
    float* SM  = ws + WS_SM;
    float* XX  = ws + WS_XX;

    dim3 blk(256);

    // 1. embed + concat
    k_embed<<<dim3(B), blk, 0, stream>>>(word, ctx, emb, X);

    // 2. LSTM chain
    k_lstm_z<<<dim3(8, B), blk, 0, stream>>>(X, K1, h1o, Wx1, Wh1, b1, Z);
    k_gates <<<dim3(2, B), blk, 0, stream>>>(Z, c1o, out + OFF_H1, out + OFF_C1);

    k_lstm_z<<<dim3(8, B), blk, 0, stream>>>(out + OFF_H1, H, h2o, Wx2, Wh2, b2, Z);
    k_gates <<<dim3(2, B), blk, 0, stream>>>(Z, c2o, out + OFF_H2, out + OFF_C2);

    k_lstm_z<<<dim3(8, B), blk, 0, stream>>>(out + OFF_H2, H, h3o, Wx3, Wh3, b3, Z);
    k_gates <<<dim3(2, B), blk, 0, stream>>>(Z, c3o, out + OFF_H3, out + OFF_C3);

    k_lstm_z<<<dim3(8, B), blk, 0, stream>>>(out + OFF_H3, H, h4o, Wx4, Wh4, b4, Z);
    k_gates <<<dim3(2, B), blk, 0, stream>>>(Z, c4o, out + OFF_H4, out + OFF_C4);

    // 3. attention decoder projections (p and m)
    k_decproj<<<dim3(2, B, 2), blk, 0, stream>>>(out + OFF_H4, pW2w, pW2b, mW2w, mW2b, D2P, D2M);

    // 4. attention scores (persona tiles 0..7, msg tiles 8..23)
    k_attscore<<<dim3(LP / TL + LM / TL, B), blk, 0, stream>>>(
        encP, encM, pW1w, pW1b, pVw, pVb, mW1w, mW1b, mVw, mVb, D2P, D2M, SP, SM);

    // 5. softmax + weighted ctx (writes p_w, m_w, ctx_new)
    k_softmax_ctx<<<dim3(B, 2), blk, 0, stream>>>(encP, encM, SP, SM, out);

    // 6. xx = concat([h4, ctx_new])
    k_buildxx<<<dim3(B), blk, 0, stream>>>(out, XX);

    // 7. logits = xx @ out_w + out_b
    k_loginit<<<dim3(V / 256, B), blk, 0, stream>>>(outb, out);
    k_logits <<<dim3(V / 256, KSPLIT), blk, 0, stream>>>(XX, outw, out);
}

// Round 2
// 950.318 us; speedup vs baseline: 1.8680x; 1.8680x over previous
//
#include <hip/hip_runtime.h>
#include <hip/hip_bf16.h>

// Problem constants
#define B 16
#define LP 128
#define LM 256
#define V 32000
#define E 512
#define H 512
#define DENC 1024          // 2*H
#define K1 2560            // E + 2*DENC
#define G4 2048            // 4*H

// d_out offsets (floats), concat order: logits, p_w, m_w, ctx_new, h1,c1,...,h4,c4
#define OFF_LOGITS 0
#define OFF_PW 512000
#define OFF_MW 514048
#define OFF_CTX 518144
#define OFF_H1 550912
#define OFF_C1 559104
#define OFF_H2 567296
#define OFF_C2 575488
#define OFF_H3 583680
#define OFF_C3 591872
#define OFF_H4 600064
#define OFF_C4 608256

#define ZSPLIT 32          // k-chunks for LSTM z GEMM
#define LSPLIT 4           // k-chunks for logits GEMM

// ws offsets (floats)
#define WS_X      0                      // B*K1 = 40960
#define WS_ZPART  40960                  // ZSPLIT*B*G4 = 1048576
#define WS_D2P    1089536                // B*H = 8192
#define WS_D2M    1097728                // B*H = 8192
#define WS_SP     1105920                // B*LP = 2048
#define WS_SM     1107968                // B*LM = 4096
#define WS_XXT    1112064                // K1*B = 40960 (transposed [k][b])
#define WS_LPART  1153024                // LSPLIT*B*V = 2048000
// total = 3201024 floats = 12.8 MB

__device__ __forceinline__ float sigm(float x) { return 1.0f / (1.0f + expf(-x)); }

// ---------------- embedding gather + concat([ctx, emb]) ----------------
__global__ void k_embed(const int* __restrict__ word, const float* __restrict__ ctx,
                        const float* __restrict__ emb, float* __restrict__ x)
{
    int b = blockIdx.x;
    int w = word[b];
    for (int i = threadIdx.x; i < 2 * DENC; i += 256) x[b * K1 + i] = ctx[b * 2 * DENC + i];
    for (int i = threadIdx.x; i < E; i += 256)        x[b * K1 + 2 * DENC + i] = emb[(size_t)w * E + i];
}

// ---------------- z partials: zpart[s][b][j] = sum_{k in chunk s} in[b][k] * W[k][j] ----------------
// in = concat(x[B][kx], h[B][H]) along k; W = concat(Wx, Wh) along k. grid (G4/256, ZSPLIT)
__global__ void k_lstm_zp(const float* __restrict__ x, int kx,
                          const float* __restrict__ h,
                          const float* __restrict__ Wx, const float* __restrict__ Wh,
                          float* __restrict__ zpart)
{
    int j = blockIdx.x * 256 + threadIdx.x;        // output column in [0, 2048)
    int K = kx + H;
    int chunk = K / ZSPLIT;                        // 96 (L1) or 32 (L2-4)
    int k0 = blockIdx.y * chunk;
    int k1 = k0 + chunk;

    __shared__ float xs[96 * 16];                  // [k - k0][b]
    for (int idx = threadIdx.x; idx < chunk * 16; idx += 256) {
        int kk = idx >> 4, b = idx & 15;
        int k = k0 + kk;
        xs[idx] = (k < kx) ? x[b * kx + k] : h[b * H + (k - kx)];
    }
    __syncthreads();

    float acc[16];
    #pragma unroll
    for (int b = 0; b < 16; ++b) acc[b] = 0.f;

    #pragma unroll 4
    for (int k = k0; k < k1; ++k) {
        float w = (k < kx) ? Wx[(size_t)k * G4 + j] : Wh[(size_t)(k - kx) * G4 + j];
        const float4* xp = (const float4*)&xs[(k - k0) * 16];
        float4 x0 = xp[0], x1 = xp[1], x2 = xp[2], x3 = xp[3];
        acc[0]  += x0.x * w; acc[1]  += x0.y * w; acc[2]  += x0.z * w; acc[3]  += x0.w * w;
        acc[4]  += x1.x * w; acc[5]  += x1.y * w; acc[6]  += x1.z * w; acc[7]  += x1.w * w;
        acc[8]  += x2.x * w; acc[9]  += x2.y * w; acc[10] += x2.z * w; acc[11] += x2.w * w;
        acc[12] += x3.x * w; acc[13] += x3.y * w; acc[14] += x3.z * w; acc[15] += x3.w * w;
    }

    float* zp = zpart + (size_t)blockIdx.y * B * G4;
    #pragma unroll
    for (int b = 0; b < 16; ++b) zp[b * G4 + j] = acc[b];
}

// ---------------- gates: reduce partials + bias, apply LSTM nonlinearity ----------------
__global__ void k_gates(const float* __restrict__ zpart, const float* __restrict__ bias,
                        const float* __restrict__ c_old,
                        float* __restrict__ h_new, float* __restrict__ c_new)
{
    int b = blockIdx.y;
    int j = blockIdx.x * 256 + threadIdx.x;        // [0, 512)
    float zi = bias[j], zf = bias[H + j], zg = bias[2 * H + j], zo = bias[3 * H + j];
    #pragma unroll
    for (int s = 0; s < ZSPLIT; ++s) {
        const float* zp = zpart + ((size_t)s * B + b) * G4;
        zi += zp[j]; zf += zp[H + j]; zg += zp[2 * H + j]; zo += zp[3 * H + j];
    }
    float c = sigm(zf) * c_old[b * H + j] + sigm(zi) * tanhf(zg);
    float hh = sigm(zo) * tanhf(c);
    c_new[b * H + j] = c;
    h_new[b * H + j] = hh;
}

// ---------------- d2 = h4@W2 + W2b  (both attentions) ----------------
__global__ void k_decproj(const float* __restrict__ h4,
                          const float* __restrict__ pW2w, const float* __restrict__ pW2b,
                          const float* __restrict__ mW2w, const float* __restrict__ mW2b,
                          float* __restrict__ d2p, float* __restrict__ d2m)
{
    int b = blockIdx.y;
    int j = blockIdx.x * 256 + threadIdx.x;        // [0, 512)
    int which = blockIdx.z;
    const float* W = which ? mW2w : pW2w;
    const float* bb = which ? mW2b : pW2b;
    float* o = which ? d2m : d2p;
    const float* hr = h4 + b * H;
    float acc = bb[j];
    #pragma unroll 8
    for (int k = 0; k < H; ++k) acc += hr[k] * W[k * H + j];
    o[b * H + j] = acc;
}

// ---------------- attention scores: s[b,l] = tanh(enc@W1 + W1b + d2)·V + Vb ----------------
#define TL 16
#define CH 128
__global__ void k_attscore(const float* __restrict__ encP, const float* __restrict__ encM,
                           const float* __restrict__ pW1w, const float* __restrict__ pW1b,
                           const float* __restrict__ pVw,  const float* __restrict__ pVb,
                           const float* __restrict__ mW1w, const float* __restrict__ mW1b,
                           const float* __restrict__ mVw,  const float* __restrict__ mVb,
                           const float* __restrict__ d2p,  const float* __restrict__ d2m,
                           float* __restrict__ sp, float* __restrict__ sm)
{
    __shared__ float smem[4352];                    // max(CH*20=2560, 256*17=4352)
    int tile = blockIdx.x, b = blockIdx.y, tid = threadIdx.x;
    const int PT = LP / TL;                         // 8 persona tiles
    const float *enc, *W1, *W1bv, *Vw, *Vbv, *d2;
    float* sout; int L, l0;
    if (tile < PT) { enc = encP; W1 = pW1w; W1bv = pW1b; Vw = pVw; Vbv = pVb; d2 = d2p; sout = sp; L = LP; l0 = tile * TL; }
    else           { enc = encM; W1 = mW1w; W1bv = mW1b; Vw = mVw; Vbv = mVb; d2 = d2m; sout = sm; L = LM; l0 = (tile - PT) * TL; }

    float accA[TL], accB[TL];
    #pragma unroll
    for (int l = 0; l < TL; ++l) { accA[l] = 0.f; accB[l] = 0.f; }

    for (int kk0 = 0; kk0 < DENC; kk0 += CH) {
        __syncthreads();
        for (int idx = tid; idx < CH * TL; idx += 256) {
            int kk = idx & (CH - 1), ll = idx >> 7;
            smem[kk * 20 + ll] = enc[(size_t)(b * L + l0 + ll) * DENC + kk0 + kk];
        }
        __syncthreads();
        for (int kk = 0; kk < CH; ++kk) {
            float wa = W1[(size_t)(kk0 + kk) * H + tid];
            float wb = W1[(size_t)(kk0 + kk) * H + 256 + tid];
            float el[TL];
            #pragma unroll
            for (int q = 0; q < TL / 4; ++q) {
                float4 t = *(const float4*)&smem[kk * 20 + q * 4];
                el[q * 4 + 0] = t.x; el[q * 4 + 1] = t.y; el[q * 4 + 2] = t.z; el[q * 4 + 3] = t.w;
            }
            #pragma unroll
            for (int l = 0; l < TL; ++l) { accA[l] += el[l] * wa; accB[l] += el[l] * wb; }
        }
    }

    float vA = Vw[tid], vB = Vw[256 + tid];
    float cA = W1bv[tid] + d2[b * H + tid];
    float cB = W1bv[256 + tid] + d2[b * H + 256 + tid];
    float contrib[TL];
    #pragma unroll
    for (int l = 0; l < TL; ++l)
        contrib[l] = tanhf(accA[l] + cA) * vA + tanhf(accB[l] + cB) * vB;

    __syncthreads();
    #pragma unroll
    for (int l = 0; l < TL; ++l) smem[tid * 17 + l] = contrib[l];
    __syncthreads();
    if (tid < TL) {
        float s = Vbv[0];
        for (int t = 0; t < 256; ++t) s += smem[t * 17 + tid];
        sout[b * L + l0 + tid] = s;
    }
}

// ---------------- softmax over L, writes p_w / m_w to d_out ----------------
__global__ void k_softmax(const float* __restrict__ sp, const float* __restrict__ sm,
                          float* __restrict__ out)
{
    int b = blockIdx.x, which = blockIdx.y, tid = threadIdx.x;
    const float* s = which ? sm : sp;
    int L = which ? LM : LP;
    float* wdst = out + (which ? (OFF_MW + b * LM) : (OFF_PW + b * LP));

    __shared__ float red[256];
    float v = (tid < L) ? s[b * L + tid] : -3.4e38f;
    red[tid] = v; __syncthreads();
    for (int off = 128; off > 0; off >>= 1) { if (tid < off) red[tid] = fmaxf(red[tid], red[tid + off]); __syncthreads(); }
    float mx = red[0]; __syncthreads();
    float e = (tid < L) ? expf(v - mx) : 0.f;
    red[tid] = e; __syncthreads();
    for (int off = 128; off > 0; off >>= 1) { if (tid < off) red[tid] += red[tid + off]; __syncthreads(); }
    if (tid < L) wdst[tid] = e / red[0];
}

// ---------------- ctx = sum_l w[l] * enc[b,l,:]  (split over d) ----------------
__global__ void k_ctx(const float* __restrict__ encP, const float* __restrict__ encM,
                      float* __restrict__ out)
{
    int b = blockIdx.y, which = blockIdx.z;
    int d = blockIdx.x * 256 + threadIdx.x;        // [0, DENC)
    const float* enc = which ? encM : encP;
    const float* w = out + (which ? (OFF_MW + b * LM) : (OFF_PW + b * LP));
    int L = which ? LM : LP;
    float acc = 0.f;
    for (int l = 0; l < L; ++l) acc += w[l] * enc[(size_t)(b * L + l) * DENC + d];
    out[OFF_CTX + b * 2 * DENC + which * DENC + d] = acc;
}

// ---------------- build xxT[k][b] = concat([h4, ctx_new]) transposed ----------------
__global__ void k_buildxxt(const float* __restrict__ out, float* __restrict__ xxt)
{
    int idx = blockIdx.x * 256 + threadIdx.x;      // [0, K1*B)
    int b = idx & 15, k = idx >> 4;
    float v = (k < H) ? out[OFF_H4 + b * H + k]
                      : out[OFF_CTX + b * 2 * DENC + (k - H)];
    xxt[idx] = v;
}

// ---------------- logits partials: lpart[s][b][v] = sum_{k in chunk} xxT[k][b] * ow[k][v] ----------------
__global__ void k_logits_p(const float* __restrict__ xxt, const float* __restrict__ ow,
                           float* __restrict__ lpart)
{
    int v = blockIdx.x * 256 + threadIdx.x;        // [0, 32000)
    int k0 = blockIdx.y * (K1 / LSPLIT);           // chunk 640
    float acc[16];
    #pragma unroll
    for (int b = 0; b < 16; ++b) acc[b] = 0.f;
    #pragma unroll 4
    for (int k = k0; k < k0 + K1 / LSPLIT; ++k) {
        float w = ow[(size_t)k * V + v];
        const float4* xp = (const float4*)&xxt[k * 16];   // uniform -> s_load
        float4 x0 = xp[0], x1 = xp[1], x2 = xp[2], x3 = xp[3];
        acc[0]  += x0.x * w; acc[1]  += x0.y * w; acc[2]  += x0.z * w; acc[3]  += x0.w * w;
        acc[4]  += x1.x * w; acc[5]  += x1.y * w; acc[6]  += x1.z * w; acc[7]  += x1.w * w;
        acc[8]  += x2.x * w; acc[9]  += x2.y * w; acc[10] += x2.z * w; acc[11] += x2.w * w;
        acc[12] += x3.x * w; acc[13] += x3.y * w; acc[14] += x3.z * w; acc[15] += x3.w * w;
    }
    #pragma unroll
    for (int b = 0; b < 16; ++b) lpart[((size_t)blockIdx.y * B + b) * V + v] = acc[b];
}

// ---------------- logits reduce + bias ----------------
__global__ void k_logits_r(const float* __restrict__ lpart, const float* __restrict__ ob,
                           float* __restrict__ out)
{
    int v = blockIdx.x * 256 + threadIdx.x;
    int b = blockIdx.y;
    float s = ob[v];
    #pragma unroll
    for (int p = 0; p < LSPLIT; ++p) s += lpart[((size_t)p * B + b) * V + v];
    out[(size_t)b * V + v] = s;
}

extern "C" void kernel_launch(void* const* d_in, const int* in_sizes, int n_in,
                              void* d_out, int out_size, void* d_ws, size_t ws_size,
                              hipStream_t stream)
{
    const int*   word = (const int*)d_in[0];
    const float* encP = (const float*)d_in[1];
    const float* encM = (const float*)d_in[2];
    const float* ctx  = (const float*)d_in[3];
    const float* h1o  = (const float*)d_in[4];
    const float* c1o  = (const float*)d_in[5];
    const float* h2o  = (const float*)d_in[6];
    const float* c2o  = (const float*)d_in[7];
    const float* h3o  = (const float*)d_in[8];
    const float* c3o  = (const float*)d_in[9];
    const float* h4o  = (const float*)d_in[10];
    const float* c4o  = (const float*)d_in[11];
    const float* emb  = (const float*)d_in[12];
    const float* Wx1 = (const float*)d_in[13]; const float* Wh1 = (const float*)d_in[14]; const float* b1 = (const float*)d_in[15];
    const float* Wx2 = (const float*)d_in[16]; const float* Wh2 = (const float*)d_in[17]; const float* b2 = (const float*)d_in[18];
    const float* Wx3 = (const float*)d_in[19]; const float* Wh3 = (const float*)d_in[20]; const float* b3 = (const float*)d_in[21];
    const float* Wx4 = (const float*)d_in[22]; const float* Wh4 = (const float*)d_in[23]; const float* b4 = (const float*)d_in[24];
    const float* pW1w = (const float*)d_in[25]; const float* pW1b = (const float*)d_in[26];
    const float* pW2w = (const float*)d_in[27]; const float* pW2b = (const float*)d_in[28];
    const float* pVw  = (const float*)d_in[29]; const float* pVb  = (const float*)d_in[30];
    const float* mW1w = (const float*)d_in[31]; const float* mW1b = (const float*)d_in[32];
    const float* mW2w = (const float*)d_in[33]; const float* mW2b = (const float*)d_in[34];
    const float* mVw  = (const float*)d_in[35]; const float* mVb  = (const float*)d_in[36];
    const float* outw = (const float*)d_in[37]; const float* outb = (const float*)d_in[38];

    float* out = (float*)d_out;
    float* ws  = (float*)d_ws;
    float* X     = ws + WS_X;
    float* ZPART = ws + WS_ZPART;
    float* D2P   = ws + WS_D2P;
    float* D2M   = ws + WS_D2M;
    float* SP    = ws + WS_SP;
    float* SM    = ws + WS_SM;
    float* XXT   = ws + WS_XXT;
    float* LPART = ws + WS_LPART;

    dim3 blk(256);

    // 1. embed + concat
    k_embed<<<dim3(B), blk, 0, stream>>>(word, ctx, emb, X);

    // 2. LSTM chain (split-K partials + fused reduce/gates)
    k_lstm_zp<<<dim3(8, ZSPLIT), blk, 0, stream>>>(X, K1, h1o, Wx1, Wh1, ZPART);
    k_gates  <<<dim3(2, B), blk, 0, stream>>>(ZPART, b1, c1o, out + OFF_H1, out + OFF_C1);

    k_lstm_zp<<<dim3(8, ZSPLIT), blk, 0, stream>>>(out + OFF_H1, H, h2o, Wx2, Wh2, ZPART);
    k_gates  <<<dim3(2, B), blk, 0, stream>>>(ZPART, b2, c2o, out + OFF_H2, out + OFF_C2);

    k_lstm_zp<<<dim3(8, ZSPLIT), blk, 0, stream>>>(out + OFF_H2, H, h3o, Wx3, Wh3, ZPART);
    k_gates  <<<dim3(2, B), blk, 0, stream>>>(ZPART, b3, c3o, out + OFF_H3, out + OFF_C3);

    k_lstm_zp<<<dim3(8, ZSPLIT), blk, 0, stream>>>(out + OFF_H3, H, h4o, Wx4, Wh4, ZPART);
    k_gates  <<<dim3(2, B), blk, 0, stream>>>(ZPART, b4, c4o, out + OFF_H4, out + OFF_C4);

    // 3. attention decoder projections (p and m)
    k_decproj<<<dim3(2, B, 2), blk, 0, stream>>>(out + OFF_H4, pW2w, pW2b, mW2w, mW2b, D2P, D2M);

    // 4. attention scores (persona tiles 0..7, msg tiles 8..23)
    k_attscore<<<dim3(LP / TL + LM / TL, B), blk, 0, stream>>>(
        encP, encM, pW1w, pW1b, pVw, pVb, mW1w, mW1b, mVw, mVb, D2P, D2M, SP, SM);

    // 5. softmax (writes p_w, m_w), then weighted ctx (writes ctx_new)
    k_softmax<<<dim3(B, 2), blk, 0, stream>>>(SP, SM, out);
    k_ctx<<<dim3(DENC / 256, B, 2), blk, 0, stream>>>(encP, encM, out);

    // 6. xxT = concat([h4, ctx_new]) transposed to [k][b]
    k_buildxxt<<<dim3(K1 * B / 256), blk, 0, stream>>>(out, XXT);

    // 7. logits = xx @ out_w + out_b (split-K partials + reduce)
    k_logits_p<<<dim3(V / 256, LSPLIT), blk, 0, stream>>>(XXT, outw, LPART);
    k_logits_r<<<dim3(V / 256, B), blk, 0, stream>>>(LPART, outb, out);
}